// Round 1
// baseline (226.613 us; speedup 1.0000x reference)
//
#include <hip/hip_runtime.h>
#include <math.h>

#define HW_ 6400
#define C_ 256
#define CP_ 19

// ---------------------------------------------------------------------------
// prep: fold BN into W_feat, transpose both weight mats to K-major.
//   scale[c] = gamma[c]*rsqrt(var[c]+eps); shift[c] = beta[c]-mean[c]*scale[c]
//   wfT[c][o] = w_feat[o][c]*scale[c];  bias[o] = sum_c w_feat[o][c]*shift[c]
//   wuT[c][o] = w_fuse[o][c]
// ---------------------------------------------------------------------------
__global__ __launch_bounds__(256) void prep_kernel(
    const float* __restrict__ wf, const float* __restrict__ wfuse,
    const float* __restrict__ g, const float* __restrict__ be,
    const float* __restrict__ mu, const float* __restrict__ var,
    float* __restrict__ wfT, float* __restrict__ wuT, float* __restrict__ bias)
{
    int o = blockIdx.x, c = threadIdx.x;
    float scale = g[c] * rsqrtf(var[c] + 1e-5f);
    float shift = be[c] - mu[c] * scale;
    float w = wf[o * C_ + c];                 // coalesced read of row o
    wfT[c * C_ + o] = w * scale;              // transposed (scattered) write, tiny
    wuT[c * C_ + o] = wfuse[o * C_ + c];
    __shared__ float red[256];
    red[c] = w * shift;
    __syncthreads();
    for (int s = 128; s > 0; s >>= 1) {
        if (c < s) red[c] += red[c + s];
        __syncthreads();
    }
    if (c == 0) bias[o] = red[0];
}

// ---------------------------------------------------------------------------
// fp32 tiled GEMM: C[M][N] = AT^T * B (+bias[row]) (+resid)
//   AT is K-major (K x M), B is (K x N). 64x64 tile, BK=16, 256 thr, 4x4/thr.
// ---------------------------------------------------------------------------
__global__ __launch_bounds__(256) void gemm_kernel(
    const float* __restrict__ AT, const float* __restrict__ B,
    const float* __restrict__ bias, const float* __restrict__ resid,
    float* __restrict__ C, int M, int N, int K)
{
    __shared__ float sA[16][64];
    __shared__ float sB[16][64];
    const int bm = blockIdx.y * 64, bn = blockIdx.x * 64;
    const int tx = threadIdx.x & 15, ty = threadIdx.x >> 4;
    const int e = threadIdx.x * 4;
    const int ka = e >> 6, ra = e & 63;       // tile element (ka, ra..ra+3)
    float acc[4][4] = {};
    for (int k0 = 0; k0 < K; k0 += 16) {
        *(float4*)&sA[ka][ra] = *(const float4*)&AT[(k0 + ka) * M + bm + ra];
        *(float4*)&sB[ka][ra] = *(const float4*)&B[(k0 + ka) * N + bn + ra];
        __syncthreads();
#pragma unroll
        for (int kk = 0; kk < 16; ++kk) {
            float a[4], b[4];
            *(float4*)a = *(const float4*)&sA[kk][ty * 4];
            *(float4*)b = *(const float4*)&sB[kk][tx * 4];
#pragma unroll
            for (int i = 0; i < 4; ++i)
#pragma unroll
                for (int j = 0; j < 4; ++j) acc[i][j] += a[i] * b[j];
        }
        __syncthreads();
    }
#pragma unroll
    for (int i = 0; i < 4; ++i) {
        int row = bm + ty * 4 + i;
        int off = row * N + bn + tx * 4;
        float bi = bias ? bias[row] : 0.0f;
        float r[4];
#pragma unroll
        for (int j = 0; j < 4; ++j) r[j] = acc[i][j] + bi;
        if (resid) {
            float x4[4];
            *(float4*)x4 = *(const float4*)&resid[off];
#pragma unroll
            for (int j = 0; j < 4; ++j) r[j] += x4[j];
        }
        *(float4*)&C[off] = *(float4*)r;
    }
}

// ---------------------------------------------------------------------------
// affinity: per pixel p, 49 neighbor weights over Cp=19 channels.
//   w_k = exp(-dist2_k/denom); out = softmax_k(w_k). Stored k-major [49][HW].
// ---------------------------------------------------------------------------
__global__ __launch_bounds__(256) void affinity_kernel(
    const float* __restrict__ cp, const float* __restrict__ sigma,
    float* __restrict__ aff)
{
    int p = blockIdx.x * 256 + threadIdx.x;   // grid = 25 -> exactly 6400
    int h = p / 80, w = p - h * 80;
    float s = fmaxf(sigma[0], 0.0f);
    float inv_denom = 1.0f / (2.0f * s * s + 1e-8f);
    float center[CP_];
#pragma unroll
    for (int c = 0; c < CP_; ++c) center[c] = cp[c * HW_ + p];
    float wgt[49];
    float mx = 0.0f;
#pragma unroll
    for (int i = 0; i < 7; ++i) {
        int hh = h + i - 3;
        bool okh = (hh >= 0) && (hh < 80);
#pragma unroll
        for (int j = 0; j < 7; ++j) {
            int ww = w + j - 3;
            bool ok = okh && (ww >= 0) && (ww < 80);
            int q = hh * 80 + ww;
            int qc = min(max(q, 0), HW_ - 1);  // clamp so load is always legal
            float msk = ok ? 1.0f : 0.0f;
            float d = 0.0f;
#pragma unroll
            for (int c = 0; c < CP_; ++c) {
                float u = cp[c * HW_ + qc] * msk;   // zero-pad semantics
                float t = u - center[c];
                d += t * t;
            }
            float val = __expf(-d * inv_denom);
            wgt[i * 7 + j] = val;
            mx = fmaxf(mx, val);
        }
    }
    float sum = 0.0f;
#pragma unroll
    for (int k = 0; k < 49; ++k) {
        float t = __expf(wgt[k] - mx);
        wgt[k] = t;
        sum += t;
    }
    float inv = 1.0f / sum;
#pragma unroll
    for (int k = 0; k < 49; ++k) aff[k * HW_ + p] = wgt[k] * inv;
}

// ---------------------------------------------------------------------------
// agg: agg[c][p] = sum_k aff[k][p] * msg[c][neighbor(p,k)]  (zero-pad OOB)
//   4 pixels per thread: float4 affinity loads, 10-wide msg row reuse.
// ---------------------------------------------------------------------------
__global__ __launch_bounds__(256) void agg_kernel(
    const float* __restrict__ msg, const float* __restrict__ aff,
    float* __restrict__ agg)
{
    int task = blockIdx.x * 256 + threadIdx.x;  // 409600 tasks = 256 * 1600
    int c = task / 1600;
    int r = task - c * 1600;
    int h = r / 20;
    int w0 = (r - h * 20) * 4;
    int p0 = h * 80 + w0;
    const float* m = msg + c * HW_;
    float acc[4] = {0.0f, 0.0f, 0.0f, 0.0f};
#pragma unroll
    for (int i = 0; i < 7; ++i) {
        int hh = h + i - 3;
        if (hh < 0 || hh >= 80) continue;
        const float* mrow = m + hh * 80;
        float mv[10];
#pragma unroll
        for (int t = 0; t < 10; ++t) {
            int ww = w0 - 3 + t;
            mv[t] = (ww >= 0 && ww < 80) ? mrow[ww] : 0.0f;
        }
#pragma unroll
        for (int j = 0; j < 7; ++j) {
            float a[4];
            *(float4*)a = *(const float4*)&aff[(i * 7 + j) * HW_ + p0];
            acc[0] += a[0] * mv[j];
            acc[1] += a[1] * mv[j + 1];
            acc[2] += a[2] * mv[j + 2];
            acc[3] += a[3] * mv[j + 3];
        }
    }
    *(float4*)&agg[c * HW_ + p0] = *(float4*)acc;
}

// ---------------------------------------------------------------------------
extern "C" void kernel_launch(void* const* d_in, const int* in_sizes, int n_in,
                              void* d_out, int out_size, void* d_ws, size_t ws_size,
                              hipStream_t stream) {
    const float* x      = (const float*)d_in[0];  // (1,256,80,80)
    const float* cp     = (const float*)d_in[1];  // (1,19,80,80)
    const float* sigma  = (const float*)d_in[2];  // (1,)
    const float* w_feat = (const float*)d_in[3];  // (256,256)
    const float* w_fuse = (const float*)d_in[4];  // (256,256)
    const float* g      = (const float*)d_in[5];
    const float* be     = (const float*)d_in[6];
    const float* mu     = (const float*)d_in[7];
    const float* var    = (const float*)d_in[8];
    float* out = (float*)d_out;

    float* ws   = (float*)d_ws;
    float* wfT  = ws;                 // 65536  (K-major folded W_feat)
    float* wuT  = wfT + 65536;        // 65536  (K-major W_fuse)
    float* bias = wuT + 65536;        // 256
    float* msgs = bias + 256;         // 1638400
    float* aff  = msgs + 1638400;     // 313600 (49 x 6400, k-major)
    float* agg  = aff + 313600;       // 1638400
    // total ~14.2 MiB of ws

    prep_kernel<<<256, 256, 0, stream>>>(w_feat, w_fuse, g, be, mu, var, wfT, wuT, bias);
    // messages = W_feat' * x + bias
    gemm_kernel<<<dim3(100, 4), 256, 0, stream>>>(wfT, x, bias, nullptr, msgs, C_, HW_, C_);
    affinity_kernel<<<25, 256, 0, stream>>>(cp, sigma, aff);
    agg_kernel<<<1600, 256, 0, stream>>>(msgs, aff, agg);
    // out = x + W_fuse * agg
    gemm_kernel<<<dim3(100, 4), 256, 0, stream>>>(wuT, agg, nullptr, x, out, C_, HW_, C_);
}

// Round 2
// 161.125 us; speedup vs baseline: 1.4064x; 1.4064x over previous
//
#include <hip/hip_runtime.h>
#include <math.h>

#define HW_ 6400
#define C_ 256
#define CP_ 19

// ---------------------------------------------------------------------------
// prep: fold BN into W_feat, transpose both weight mats to K-major.
//   scale[c] = gamma[c]*rsqrt(var[c]+eps); shift[c] = beta[c]-mean[c]*scale[c]
//   wfT[c][o] = w_feat[o][c]*scale[c];  bias[o] = sum_c w_feat[o][c]*shift[c]
//   wuT[c][o] = w_fuse[o][c]
// ---------------------------------------------------------------------------
__global__ __launch_bounds__(256) void prep_kernel(
    const float* __restrict__ wf, const float* __restrict__ wfuse,
    const float* __restrict__ g, const float* __restrict__ be,
    const float* __restrict__ mu, const float* __restrict__ var,
    float* __restrict__ wfT, float* __restrict__ wuT, float* __restrict__ bias)
{
    int o = blockIdx.x, c = threadIdx.x;
    float scale = g[c] * rsqrtf(var[c] + 1e-5f);
    float shift = be[c] - mu[c] * scale;
    float w = wf[o * C_ + c];                 // coalesced read of row o
    wfT[c * C_ + o] = w * scale;              // transposed (scattered) write, tiny
    wuT[c * C_ + o] = wfuse[o * C_ + c];
    __shared__ float red[256];
    red[c] = w * shift;
    __syncthreads();
    for (int s = 128; s > 0; s >>= 1) {
        if (c < s) red[c] += red[c + s];
        __syncthreads();
    }
    if (c == 0) bias[o] = red[0];
}

// ---------------------------------------------------------------------------
// fp32 tiled GEMM: C[M][N] = AT^T * B (+bias[row]) (+resid)
//   AT is K-major (K x M), B is (K x N). 64x64 tile, BK=16, 256 thr, 4x4/thr.
// ---------------------------------------------------------------------------
__global__ __launch_bounds__(256) void gemm_kernel(
    const float* __restrict__ AT, const float* __restrict__ B,
    const float* __restrict__ bias, const float* __restrict__ resid,
    float* __restrict__ C, int M, int N, int K)
{
    __shared__ float sA[16][64];
    __shared__ float sB[16][64];
    const int bm = blockIdx.y * 64, bn = blockIdx.x * 64;
    const int tx = threadIdx.x & 15, ty = threadIdx.x >> 4;
    const int e = threadIdx.x * 4;
    const int ka = e >> 6, ra = e & 63;       // tile element (ka, ra..ra+3)
    float acc[4][4] = {};
    for (int k0 = 0; k0 < K; k0 += 16) {
        *(float4*)&sA[ka][ra] = *(const float4*)&AT[(k0 + ka) * M + bm + ra];
        *(float4*)&sB[ka][ra] = *(const float4*)&B[(k0 + ka) * N + bn + ra];
        __syncthreads();
#pragma unroll
        for (int kk = 0; kk < 16; ++kk) {
            float a[4], b[4];
            *(float4*)a = *(const float4*)&sA[kk][ty * 4];
            *(float4*)b = *(const float4*)&sB[kk][tx * 4];
#pragma unroll
            for (int i = 0; i < 4; ++i)
#pragma unroll
                for (int j = 0; j < 4; ++j) acc[i][j] += a[i] * b[j];
        }
        __syncthreads();
    }
#pragma unroll
    for (int i = 0; i < 4; ++i) {
        int row = bm + ty * 4 + i;
        int off = row * N + bn + tx * 4;
        float bi = bias ? bias[row] : 0.0f;
        float r[4];
#pragma unroll
        for (int j = 0; j < 4; ++j) r[j] = acc[i][j] + bi;
        if (resid) {
            float x4[4];
            *(float4*)x4 = *(const float4*)&resid[off];
#pragma unroll
            for (int j = 0; j < 4; ++j) r[j] += x4[j];
        }
        *(float4*)&C[off] = *(float4*)r;
    }
}

// ---------------------------------------------------------------------------
// affinity v2: one wave per pixel, one lane per neighbor k (49 of 64 lanes).
//   lane k: d = sum_c (u_k[c]*pad_mask - center[c])^2, center via shfl(lane24)
//   raw = exp(-d/denom); softmax over 49 k's via wave shfl_xor sum.
//   Output k-major: aff[k][HW].
// ---------------------------------------------------------------------------
__global__ __launch_bounds__(256) void affinity_kernel(
    const float* __restrict__ cp, const float* __restrict__ sigma,
    float* __restrict__ aff)
{
    const int lane = threadIdx.x & 63;
    const int p = blockIdx.x * 4 + (threadIdx.x >> 6);   // 1600 blocks -> 6400 px
    const int h = p / 80, w = p - h * 80;
    const int k = (lane < 49) ? lane : 48;
    const int i = k / 7, j = k - i * 7;
    const int hh = h + i - 3, ww = w + j - 3;
    const bool ok = (hh >= 0) & (hh < 80) & (ww >= 0) & (ww < 80);
    const float msk = ok ? 1.0f : 0.0f;                  // zero-pad semantics
    int q = hh * 80 + ww;
    q = min(max(q, 0), HW_ - 1);                         // always-legal address

    float s = fmaxf(sigma[0], 0.0f);
    float inv_denom = 1.0f / (2.0f * s * s + 1e-8f);

    float d = 0.0f;
#pragma unroll
    for (int c = 0; c < CP_; ++c) {
        float u = cp[c * HW_ + q];
        float ctr = __shfl(u, 24, 64);                   // lane 24 == center px
        float t = u * msk - ctr;
        d += t * t;
    }
    float raw = __expf(-d * inv_denom);
    float e = (lane < 49) ? __expf(raw) : 0.0f;          // softmax numerator
    float sum = e;
#pragma unroll
    for (int off = 32; off; off >>= 1) sum += __shfl_xor(sum, off, 64);
    if (lane < 49) aff[k * HW_ + p] = e / sum;
}

// ---------------------------------------------------------------------------
// agg: agg[c][p] = sum_k aff[k][p] * msg[c][neighbor(p,k)]  (zero-pad OOB)
//   4 pixels per thread: float4 affinity loads, 10-wide msg row reuse.
// ---------------------------------------------------------------------------
__global__ __launch_bounds__(256) void agg_kernel(
    const float* __restrict__ msg, const float* __restrict__ aff,
    float* __restrict__ agg)
{
    int task = blockIdx.x * 256 + threadIdx.x;  // 409600 tasks = 256 * 1600
    int c = task / 1600;
    int r = task - c * 1600;
    int h = r / 20;
    int w0 = (r - h * 20) * 4;
    int p0 = h * 80 + w0;
    const float* m = msg + c * HW_;
    float acc[4] = {0.0f, 0.0f, 0.0f, 0.0f};
#pragma unroll
    for (int i = 0; i < 7; ++i) {
        int hh = h + i - 3;
        if (hh < 0 || hh >= 80) continue;
        const float* mrow = m + hh * 80;
        float mv[10];
#pragma unroll
        for (int t = 0; t < 10; ++t) {
            int ww = w0 - 3 + t;
            mv[t] = (ww >= 0 && ww < 80) ? mrow[ww] : 0.0f;
        }
#pragma unroll
        for (int j = 0; j < 7; ++j) {
            float a[4];
            *(float4*)a = *(const float4*)&aff[(i * 7 + j) * HW_ + p0];
            acc[0] += a[0] * mv[j];
            acc[1] += a[1] * mv[j + 1];
            acc[2] += a[2] * mv[j + 2];
            acc[3] += a[3] * mv[j + 3];
        }
    }
    *(float4*)&agg[c * HW_ + p0] = *(float4*)acc;
}

// ---------------------------------------------------------------------------
extern "C" void kernel_launch(void* const* d_in, const int* in_sizes, int n_in,
                              void* d_out, int out_size, void* d_ws, size_t ws_size,
                              hipStream_t stream) {
    const float* x      = (const float*)d_in[0];  // (1,256,80,80)
    const float* cp     = (const float*)d_in[1];  // (1,19,80,80)
    const float* sigma  = (const float*)d_in[2];  // (1,)
    const float* w_feat = (const float*)d_in[3];  // (256,256)
    const float* w_fuse = (const float*)d_in[4];  // (256,256)
    const float* g      = (const float*)d_in[5];
    const float* be     = (const float*)d_in[6];
    const float* mu     = (const float*)d_in[7];
    const float* var    = (const float*)d_in[8];
    float* out = (float*)d_out;

    float* ws   = (float*)d_ws;
    float* wfT  = ws;                 // 65536  (K-major folded W_feat)
    float* wuT  = wfT + 65536;        // 65536  (K-major W_fuse)
    float* bias = wuT + 65536;        // 256
    float* msgs = bias + 256;         // 1638400
    float* aff  = msgs + 1638400;     // 313600 (49 x 6400, k-major)
    float* agg  = aff + 313600;       // 1638400
    // total ~14.2 MiB of ws

    prep_kernel<<<256, 256, 0, stream>>>(w_feat, w_fuse, g, be, mu, var, wfT, wuT, bias);
    // messages = W_feat' * x + bias
    gemm_kernel<<<dim3(100, 4), 256, 0, stream>>>(wfT, x, bias, nullptr, msgs, C_, HW_, C_);
    affinity_kernel<<<1600, 256, 0, stream>>>(cp, sigma, aff);
    agg_kernel<<<1600, 256, 0, stream>>>(msgs, aff, agg);
    // out = x + W_fuse * agg
    gemm_kernel<<<dim3(100, 4), 256, 0, stream>>>(wuT, agg, nullptr, x, out, C_, HW_, C_);
}

// Round 3
// 151.377 us; speedup vs baseline: 1.4970x; 1.0644x over previous
//
#include <hip/hip_runtime.h>
#include <math.h>

#define HW_ 6400
#define C_ 256
#define CP_ 19

// ---------------------------------------------------------------------------
// wgemm: W = W_fuse @ W_feat (256x256x256), BN folded into epilogue terms.
//   block o, thread c:
//     W[o][c]  = sum_m wfuse[o][m] * wfeat[m][c]
//     WT[c][o] = W[o][c] * scale[c]          (K-major for main GEMM)
//     wsum[o]  = sum_c W[o][c] * shift[c]    (rank-1 zero-pad correction)
// ---------------------------------------------------------------------------
__global__ __launch_bounds__(256) void wgemm_kernel(
    const float* __restrict__ wfeat, const float* __restrict__ wfuse,
    const float* __restrict__ g, const float* __restrict__ be,
    const float* __restrict__ mu, const float* __restrict__ var,
    float* __restrict__ WT, float* __restrict__ wsum)
{
    const int o = blockIdx.x, c = threadIdx.x;
    __shared__ float row[C_];
    __shared__ float red[C_];
    row[c] = wfuse[o * C_ + c];
    __syncthreads();
    float acc = 0.0f;
#pragma unroll 8
    for (int m = 0; m < C_; ++m) acc += row[m] * wfeat[m * C_ + c];
    float scale = g[c] * rsqrtf(var[c] + 1e-5f);
    float shift = be[c] - mu[c] * scale;
    WT[c * C_ + o] = acc * scale;
    red[c] = acc * shift;
    __syncthreads();
    for (int s = 128; s > 0; s >>= 1) {
        if (c < s) red[c] += red[c + s];
        __syncthreads();
    }
    if (c == 0) wsum[o] = red[0];
}

// ---------------------------------------------------------------------------
// affinity: one wave per pixel, one lane per neighbor k (49 of 64 lanes).
//   lane k: d = sum_c (u_k[c]*pad_mask - center[c])^2, center via shfl(lane24)
//   raw = exp(-d/denom); softmax over 49 via wave shfl_xor sum.
//   Also S[p] = sum of softmax weights whose neighbor is in-bounds.
// ---------------------------------------------------------------------------
__global__ __launch_bounds__(256) void affinity_kernel(
    const float* __restrict__ cp, const float* __restrict__ sigma,
    float* __restrict__ aff, float* __restrict__ S)
{
    const int lane = threadIdx.x & 63;
    const int p = blockIdx.x * 4 + (threadIdx.x >> 6);   // 1600 blocks -> 6400 px
    const int h = p / 80, w = p - h * 80;
    const int k = (lane < 49) ? lane : 48;
    const int i = k / 7, j = k - i * 7;
    const int hh = h + i - 3, ww = w + j - 3;
    const bool ok = (hh >= 0) & (hh < 80) & (ww >= 0) & (ww < 80);
    const float msk = ok ? 1.0f : 0.0f;                  // zero-pad semantics
    int q = hh * 80 + ww;
    q = min(max(q, 0), HW_ - 1);                         // always-legal address

    float s = fmaxf(sigma[0], 0.0f);
    float inv_denom = 1.0f / (2.0f * s * s + 1e-8f);

    float d = 0.0f;
#pragma unroll
    for (int c = 0; c < CP_; ++c) {
        float u = cp[c * HW_ + q];
        float ctr = __shfl(u, 24, 64);                   // lane 24 == center px
        float t = u * msk - ctr;
        d += t * t;
    }
    float raw = __expf(-d * inv_denom);
    float e = (lane < 49) ? __expf(raw) : 0.0f;          // softmax numerator
    float einb = (ok && lane < 49) ? e : 0.0f;
    float sum = e, sumi = einb;
#pragma unroll
    for (int off = 32; off; off >>= 1) {
        sum  += __shfl_xor(sum,  off, 64);
        sumi += __shfl_xor(sumi, off, 64);
    }
    if (lane < 49) aff[k * HW_ + p] = e / sum;
    if (lane == 0) S[p] = sumi / sum;
}

// ---------------------------------------------------------------------------
// aggx: aggx[c][p] = sum_k aff[k][p] * x[c][neighbor(p,k)]  (zero-pad OOB)
//   Raw x input (BN folded downstream). 4 px/thread, float4 aff loads.
// ---------------------------------------------------------------------------
__global__ __launch_bounds__(256) void aggx_kernel(
    const float* __restrict__ x, const float* __restrict__ aff,
    float* __restrict__ agg)
{
    int task = blockIdx.x * 256 + threadIdx.x;  // 409600 tasks = 256 * 1600
    int c = task / 1600;
    int r = task - c * 1600;
    int h = r / 20;
    int w0 = (r - h * 20) * 4;
    int p0 = h * 80 + w0;
    const float* m = x + c * HW_;
    float acc[4] = {0.0f, 0.0f, 0.0f, 0.0f};
#pragma unroll
    for (int i = 0; i < 7; ++i) {
        int hh = h + i - 3;
        if (hh < 0 || hh >= 80) continue;
        const float* mrow = m + hh * 80;
        float mv[10];
#pragma unroll
        for (int t = 0; t < 10; ++t) {
            int ww = w0 - 3 + t;
            mv[t] = (ww >= 0 && ww < 80) ? mrow[ww] : 0.0f;
        }
#pragma unroll
        for (int j = 0; j < 7; ++j) {
            float a[4];
            *(float4*)a = *(const float4*)&aff[(i * 7 + j) * HW_ + p0];
            acc[0] += a[0] * mv[j];
            acc[1] += a[1] * mv[j + 1];
            acc[2] += a[2] * mv[j + 2];
            acc[3] += a[3] * mv[j + 3];
        }
    }
    *(float4*)&agg[c * HW_ + p0] = *(float4*)acc;
}

// ---------------------------------------------------------------------------
// main GEMM: out[o][p] = x[o][p] + wsum[o]*S[p] + sum_c WT[c][o]*aggx[c][p]
//   WT K-major (K x M), B (K x N). 64x64 tile, BK=16, 256 thr, 4x4/thr.
// ---------------------------------------------------------------------------
__global__ __launch_bounds__(256) void gemm_kernel(
    const float* __restrict__ AT, const float* __restrict__ B,
    const float* __restrict__ wsum, const float* __restrict__ S,
    const float* __restrict__ resid, float* __restrict__ C,
    int M, int N, int K)
{
    __shared__ float sA[16][64];
    __shared__ float sB[16][64];
    const int bm = blockIdx.y * 64, bn = blockIdx.x * 64;
    const int tx = threadIdx.x & 15, ty = threadIdx.x >> 4;
    const int e = threadIdx.x * 4;
    const int ka = e >> 6, ra = e & 63;       // tile element (ka, ra..ra+3)
    float acc[4][4] = {};
    for (int k0 = 0; k0 < K; k0 += 16) {
        *(float4*)&sA[ka][ra] = *(const float4*)&AT[(k0 + ka) * M + bm + ra];
        *(float4*)&sB[ka][ra] = *(const float4*)&B[(k0 + ka) * N + bn + ra];
        __syncthreads();
#pragma unroll
        for (int kk = 0; kk < 16; ++kk) {
            float a[4], b[4];
            *(float4*)a = *(const float4*)&sA[kk][ty * 4];
            *(float4*)b = *(const float4*)&sB[kk][tx * 4];
#pragma unroll
            for (int i = 0; i < 4; ++i)
#pragma unroll
                for (int j = 0; j < 4; ++j) acc[i][j] += a[i] * b[j];
        }
        __syncthreads();
    }
    float s4[4];
    *(float4*)s4 = *(const float4*)&S[bn + tx * 4];
#pragma unroll
    for (int i = 0; i < 4; ++i) {
        int row = bm + ty * 4 + i;
        int off = row * N + bn + tx * 4;
        float ws = wsum[row];
        float x4[4];
        *(float4*)x4 = *(const float4*)&resid[off];
        float r[4];
#pragma unroll
        for (int j = 0; j < 4; ++j) r[j] = acc[i][j] + ws * s4[j] + x4[j];
        *(float4*)&C[off] = *(float4*)r;
    }
}

// ---------------------------------------------------------------------------
extern "C" void kernel_launch(void* const* d_in, const int* in_sizes, int n_in,
                              void* d_out, int out_size, void* d_ws, size_t ws_size,
                              hipStream_t stream) {
    const float* x      = (const float*)d_in[0];  // (1,256,80,80)
    const float* cp     = (const float*)d_in[1];  // (1,19,80,80)
    const float* sigma  = (const float*)d_in[2];  // (1,)
    const float* w_feat = (const float*)d_in[3];  // (256,256)
    const float* w_fuse = (const float*)d_in[4];  // (256,256)
    const float* g      = (const float*)d_in[5];
    const float* be     = (const float*)d_in[6];
    const float* mu     = (const float*)d_in[7];
    const float* var    = (const float*)d_in[8];
    float* out = (float*)d_out;

    float* ws_f = (float*)d_ws;
    float* WT   = ws_f;               // 65536  (K-major W = wfuse@wfeat, x scale)
    float* wsum = WT + 65536;         // 256
    float* aff  = wsum + 256;         // 313600 (49 x 6400, k-major)
    float* S    = aff + 313600;       // 6400
    float* aggx = S + 6400;           // 1638400
    // total ~8.1 MiB of ws

    wgemm_kernel<<<256, 256, 0, stream>>>(w_feat, w_fuse, g, be, mu, var, WT, wsum);
    affinity_kernel<<<1600, 256, 0, stream>>>(cp, sigma, aff, S);
    aggx_kernel<<<1600, 256, 0, stream>>>(x, aff, aggx);
    // out = x + wsum*S + W' * aggx
    gemm_kernel<<<dim3(100, 4), 256, 0, stream>>>(WT, aggx, wsum, S, x, out, C_, HW_, C_);
}